// Round 1
// baseline (64.282 us; speedup 1.0000x reference)
//
#include <hip/hip_runtime.h>
#include <math.h>

namespace {
constexpr int KB    = 16;        // spline bins
constexpr int OUTP  = 3*KB + 1;  // 49
constexpr int CDIM  = 64;
constexpr int HDIM  = 256;
constexpr int NCOL  = 1024;
constexpr int NROW  = 4096;
constexpr float BOUNDF = 5.0f;
constexpr float MBW_ = 0.001f;
constexpr float MBH_ = 0.001f;
constexpr float MD_  = 0.001f;
constexpr int RPB  = 8;   // rows per block in MLP kernel
constexpr int PSTR = 83;  // 17 cumw + 16 widths + 17 cumh + 16 heights + 17 deriv
}

// ---------------------------------------------------------------------------
// Kernel 1: per-row MLP -> spline parameters (packed 83 floats/row into d_ws)
// Layout per row: [0..16] cumw, [17..32] widths, [33..49] cumh,
//                 [50..65] heights, [66..82] deriv
// ---------------------------------------------------------------------------
__global__ __launch_bounds__(256) void mlp_params_kernel(
    const float* __restrict__ cond,
    const float* __restrict__ W1, const float* __restrict__ b1,
    const float* __restrict__ W2, const float* __restrict__ b2,
    const float* __restrict__ W3, const float* __restrict__ b3,
    float* __restrict__ params)
{
    __shared__ float cond_s[RPB][CDIM];
    __shared__ float h1_s[RPB][HDIM];
    __shared__ float h2_s[RPB][HDIM];
    __shared__ float p_s[RPB][OUTP];
    __shared__ float prm_s[RPB][PSTR];

    const int tid  = threadIdx.x;
    const int row0 = blockIdx.x * RPB;

    // stage cond rows
    for (int i = tid; i < RPB*CDIM; i += 256) {
        const int r = i >> 6, c = i & (CDIM-1);
        cond_s[r][c] = cond[(size_t)(row0 + r)*CDIM + c];
    }
    __syncthreads();

    // layer 1: h1 = relu(cond @ W1 + b1); thread tid owns hidden unit tid
    {
        float acc[RPB];
        const float bb = b1[tid];
        #pragma unroll
        for (int r = 0; r < RPB; ++r) acc[r] = bb;
        #pragma unroll 4
        for (int c4 = 0; c4 < CDIM/4; ++c4) {
            const float w0 = W1[(c4*4+0)*HDIM + tid];
            const float w1 = W1[(c4*4+1)*HDIM + tid];
            const float w2 = W1[(c4*4+2)*HDIM + tid];
            const float w3 = W1[(c4*4+3)*HDIM + tid];
            #pragma unroll
            for (int r = 0; r < RPB; ++r) {
                const float4 cv = *(const float4*)&cond_s[r][c4*4];
                acc[r] = fmaf(cv.x, w0, acc[r]);
                acc[r] = fmaf(cv.y, w1, acc[r]);
                acc[r] = fmaf(cv.z, w2, acc[r]);
                acc[r] = fmaf(cv.w, w3, acc[r]);
            }
        }
        #pragma unroll
        for (int r = 0; r < RPB; ++r) h1_s[r][tid] = fmaxf(acc[r], 0.f);
    }
    __syncthreads();

    // layer 2: h2 = relu(h1 @ W2 + b2)
    {
        float acc[RPB];
        const float bb = b2[tid];
        #pragma unroll
        for (int r = 0; r < RPB; ++r) acc[r] = bb;
        #pragma unroll 2
        for (int k4 = 0; k4 < HDIM/4; ++k4) {
            const float w0 = W2[(k4*4+0)*HDIM + tid];
            const float w1 = W2[(k4*4+1)*HDIM + tid];
            const float w2 = W2[(k4*4+2)*HDIM + tid];
            const float w3 = W2[(k4*4+3)*HDIM + tid];
            #pragma unroll
            for (int r = 0; r < RPB; ++r) {
                const float4 hv = *(const float4*)&h1_s[r][k4*4];
                acc[r] = fmaf(hv.x, w0, acc[r]);
                acc[r] = fmaf(hv.y, w1, acc[r]);
                acc[r] = fmaf(hv.z, w2, acc[r]);
                acc[r] = fmaf(hv.w, w3, acc[r]);
            }
        }
        #pragma unroll
        for (int r = 0; r < RPB; ++r) h2_s[r][tid] = fmaxf(acc[r], 0.f);
    }
    __syncthreads();

    // layer 3: p = h2 @ W3 + b3  (RPB*49 = 392 dot products, tasks over threads)
    for (int task = tid; task < RPB*OUTP; task += 256) {
        const int r = task / OUTP;
        const int o = task - r*OUTP;
        float acc = b3[o];
        #pragma unroll 2
        for (int k4 = 0; k4 < HDIM/4; ++k4) {
            const float4 hv = *(const float4*)&h2_s[r][k4*4];
            acc = fmaf(hv.x, W3[(k4*4+0)*OUTP + o], acc);
            acc = fmaf(hv.y, W3[(k4*4+1)*OUTP + o], acc);
            acc = fmaf(hv.z, W3[(k4*4+2)*OUTP + o], acc);
            acc = fmaf(hv.w, W3[(k4*4+3)*OUTP + o], acc);
        }
        p_s[r][o] = acc;
    }
    __syncthreads();

    // softmax + cumsum + softplus: 3 serial tasks per row (tiny, 16/17 elems)
    if (tid < RPB*3) {
        const int r   = tid / 3;
        const int seg = tid - 3*r;
        if (seg < 2) {
            const int   off   = (seg == 0) ? 0  : KB;
            const int   cbase = (seg == 0) ? 0  : 33;
            const int   wbase = (seg == 0) ? 17 : 50;
            const float mb    = (seg == 0) ? MBW_ : MBH_;
            float m = -1e30f;
            #pragma unroll
            for (int i = 0; i < KB; ++i) m = fmaxf(m, p_s[r][off+i]);
            float e[KB];
            float s = 0.f;
            #pragma unroll
            for (int i = 0; i < KB; ++i) { e[i] = expf(p_s[r][off+i] - m); s += e[i]; }
            const float span = (2.f*BOUNDF - (float)KB*mb) / s;
            float c = -BOUNDF;
            prm_s[r][cbase] = c;
            #pragma unroll
            for (int i = 0; i < KB; ++i) {
                const float w = mb + span*e[i];
                prm_s[r][wbase + i] = w;
                c += w;
                prm_s[r][cbase + 1 + i] = c;
            }
        } else {
            #pragma unroll
            for (int i = 0; i < KB+1; ++i) {
                const float x  = p_s[r][2*KB + i];
                const float sp = (x > 20.f) ? x : log1pf(expf(x));
                prm_s[r][66 + i] = MD_ + sp;
            }
        }
    }
    __syncthreads();

    // coalesced dump of packed params (RPB*83 contiguous floats)
    for (int i = tid; i < RPB*PSTR; i += 256) {
        params[(size_t)row0*PSTR + i] = (&prm_s[0][0])[i];
    }
}

// ---------------------------------------------------------------------------
// Kernel 2: apply RQ spline elementwise. One block per row; float4 I/O.
// ---------------------------------------------------------------------------
__global__ __launch_bounds__(256) void spline_kernel(
    const float* __restrict__ y,
    const float* __restrict__ params,
    float* __restrict__ out,
    float* __restrict__ logdet)
{
    __shared__ float prm[PSTR];
    const int b   = blockIdx.x;
    const int tid = threadIdx.x;
    if (tid < PSTR) prm[tid] = params[(size_t)b*PSTR + tid];
    __syncthreads();

    const float* cumw    = prm;
    const float* widths  = prm + 17;
    const float* cumh    = prm + 33;
    const float* heights = prm + 50;
    const float* deriv   = prm + 66;

    // hoist bin-search thresholds into registers (static indices after unroll)
    float cw[KB];
    #pragma unroll
    for (int k = 0; k < KB; ++k) cw[k] = cumw[k+1];

    const int    n0   = tid * 4;
    const size_t base = (size_t)b * NCOL + n0;
    const float4 yv   = *(const float4*)(y + base);
    const float  yy[4] = {yv.x, yv.y, yv.z, yv.w};
    float ov[4], lv[4];

    #pragma unroll
    for (int i = 0; i < 4; ++i) {
        const float yi = yy[i];
        const bool outside = (yi < -BOUNDF) || (yi > BOUNDF);
        const float xc = fminf(fmaxf(yi, -BOUNDF), BOUNDF);
        int bin = 0;
        #pragma unroll
        for (int k = 0; k < KB; ++k) bin += (xc >= cw[k]) ? 1 : 0;
        bin = min(bin, KB-1);

        const float x0 = cumw[bin];
        const float w  = widths[bin];
        const float y0 = cumh[bin];
        const float hh = heights[bin];
        const float d0 = deriv[bin];
        const float d1 = deriv[bin+1];

        const float delta = hh / w;
        const float theta = (xc - x0) / w;
        const float omt   = 1.f - theta;
        const float tt    = theta * theta;
        const float tomt  = theta * omt;
        const float num   = hh * (delta*tt + d0*tomt);
        const float den   = delta + (d0 + d1 - 2.f*delta)*tomt;
        const float o     = y0 + num/den;
        const float der_num = fmaxf(delta*delta*(d1*tt + 2.f*delta*tomt + d0*omt*omt), 1e-12f);
        const float der_den = fmaxf(den*den, 1e-12f);
        const float ld      = logf(der_num) - logf(der_den);

        ov[i] = outside ? yi : o;
        lv[i] = outside ? 0.f : ld;
    }

    *(float4*)(out + base)    = make_float4(ov[0], ov[1], ov[2], ov[3]);
    *(float4*)(logdet + base) = make_float4(lv[0], lv[1], lv[2], lv[3]);
}

extern "C" void kernel_launch(void* const* d_in, const int* in_sizes, int n_in,
                              void* d_out, int out_size, void* d_ws, size_t ws_size,
                              hipStream_t stream) {
    const float* cond = (const float*)d_in[0];
    const float* y    = (const float*)d_in[1];
    const float* W1   = (const float*)d_in[2];
    const float* b1   = (const float*)d_in[3];
    const float* W2   = (const float*)d_in[4];
    const float* b2   = (const float*)d_in[5];
    const float* W3   = (const float*)d_in[6];
    const float* b3   = (const float*)d_in[7];

    float* out    = (float*)d_out;
    float* logdet = out + (size_t)NROW * NCOL;
    float* params = (float*)d_ws;   // NROW * PSTR floats = 1.36 MB

    mlp_params_kernel<<<NROW/RPB, 256, 0, stream>>>(cond, W1, b1, W2, b2, W3, b3, params);
    spline_kernel<<<NROW, 256, 0, stream>>>(y, params, out, logdet);
}